// Round 4
// baseline (510.112 us; speedup 1.0000x reference)
//
#include <hip/hip_runtime.h>
#include <hip/hip_bf16.h>

typedef __bf16 bf16x8 __attribute__((ext_vector_type(8)));
typedef float f32x4 __attribute__((ext_vector_type(4)));
typedef unsigned short ushort_t;

constexpr int NB = 32768;   // batch rows
constexpr int D1 = 1024;    // K
constexpr int D2 = 4096;    // N
constexpr float BETA_LOG2E = 14.4269504088896340736f; // 10 * log2(e)

__device__ __forceinline__ ushort_t f32_to_bf16(float f) {
  union { float f; unsigned int u; } x; x.f = f;
  unsigned int r = x.u + 0x7FFFu + ((x.u >> 16) & 1u);  // RNE
  return (ushort_t)(r >> 16);
}

__device__ __forceinline__ void async_copy16(const void* g, void* l) {
  __builtin_amdgcn_global_load_lds(
      (const __attribute__((address_space(1))) void*)g,
      (__attribute__((address_space(3))) void*)l, 16, 0, 0);
}

// ---- 1. partial column sum-of-squares of W: sq[j] += sum_k W[k][j]^2 ----
__global__ void colnorm_partial(const float* __restrict__ W, float* __restrict__ sq) {
  int j = blockIdx.x * 256 + threadIdx.x;   // gridDim.x = 16
  int k0 = blockIdx.y * 64;                 // gridDim.y = 16
  float acc = 0.f;
#pragma unroll 8
  for (int k = 0; k < 64; ++k) {
    float w = W[(size_t)(k0 + k) * D2 + j];
    acc += w * w;
  }
  atomicAdd(&sq[j], acc);
}

// ---- 2. g1 fp32 -> bf16, row-major [NB][D1] ----
__global__ void convert_a(const float* __restrict__ g1, ushort_t* __restrict__ g1b) {
  size_t i = ((size_t)blockIdx.x * 256 + threadIdx.x) * 8;
  float4 v0 = *(const float4*)(g1 + i);
  float4 v1 = *(const float4*)(g1 + i + 4);
  uint4 o;
  o.x = f32_to_bf16(v0.x) | ((unsigned)f32_to_bf16(v0.y) << 16);
  o.y = f32_to_bf16(v0.z) | ((unsigned)f32_to_bf16(v0.w) << 16);
  o.z = f32_to_bf16(v1.x) | ((unsigned)f32_to_bf16(v1.y) << 16);
  o.w = f32_to_bf16(v1.z) | ((unsigned)f32_to_bf16(v1.w) << 16);
  *(uint4*)(g1b + i) = o;
}

// ---- 3. normalize + transpose: nWt[j][k] = bf16(W[k][j] / sqrt(sq[j])) ----
__global__ void convert_b(const float* __restrict__ W, const float* __restrict__ sq,
                          ushort_t* __restrict__ nWt) {
  __shared__ float tile[64][65];
  int t = threadIdx.x;                 // 256
  int j0 = blockIdx.x * 64;            // gridDim.x = 64
  int k0 = blockIdx.y * 64;            // gridDim.y = 16
  int c = t & 63, r4 = t >> 6;
#pragma unroll
  for (int s = 0; s < 16; ++s) {
    int k = s * 4 + r4;
    tile[k][c] = W[(size_t)(k0 + k) * D2 + j0 + c];
  }
  __syncthreads();
#pragma unroll
  for (int s = 0; s < 16; ++s) {
    int jj = s * 4 + r4;
    float inv = 1.0f / sqrtf(sq[j0 + jj]);
    nWt[(size_t)(j0 + jj) * D1 + k0 + c] = f32_to_bf16(tile[c][jj] * inv);
  }
}

// ---- 4. fused GEMM + exp-sum. A[NB][D1] bf16, Bt[D2][D1] bf16 (both K-major).
// 128x128 tile, BK=64, 256 thr = 4 waves in 2x2, each wave 4x4 of 16x16x32 MFMA.
// Grid: x = col-blocks (32, fast axis), y = row-blocks (256) -> A-panel L2 reuse.
// LDS XOR-swizzled (seg ^= row&7) -> 0 bank conflicts.
// K-loop restructured AITER-style: preload ALL fragments into registers,
// barrier (lgkm-only), issue next tile's global_load_lds, THEN the 32-MFMA
// phase covers the vmcnt drain at the trailing barrier.
__global__ __launch_bounds__(256, 3)
void gemm_expsum(const ushort_t* __restrict__ A, const ushort_t* __restrict__ Bt,
                 float* __restrict__ s) {
  __shared__ __align__(16) ushort_t As[128 * 64];
  __shared__ __align__(16) ushort_t Bs[128 * 64];

  const int t = threadIdx.x;
  const int row0 = blockIdx.y * 128;   // gridDim.y = 256
  const int col0 = blockIdx.x * 128;   // gridDim.x = 32
  const int lane = t & 63;
  const int wave = t >> 6;
  const int wm = (wave >> 1) * 64;     // wave row offset in tile
  const int wn = (wave & 1) * 64;      // wave col offset in tile
  const int llo = lane & 15, lhi = lane >> 4;

  f32x4 acc[4][4] = {};

  // staging: thread t owns LDS slot (row=t>>3, seg=t&7); fetches global
  // segment (t&7) ^ ((t>>3)&7). Sweep i advances row by 32 (multiple of 8,
  // so row&7 — and hence the swizzle — is i-invariant).
  const int srow = t >> 3;
  const int sseg = (t & 7) ^ (srow & 7);
  const ushort_t* gA = A  + (size_t)(row0 + srow) * D1 + sseg * 8;
  const ushort_t* gB = Bt + (size_t)(col0 + srow) * D1 + sseg * 8;
  ushort_t* lA = As + t * 8;   // byte offset t*16 (lane-order contiguous)
  ushort_t* lB = Bs + t * 8;

  // prologue: stage tile 0
#pragma unroll
  for (int i = 0; i < 4; ++i) {
    async_copy16(gA + (size_t)i * 32 * D1, lA + i * 2048);
    async_copy16(gB + (size_t)i * 32 * D1, lB + i * 2048);
  }
  __syncthreads();

  for (int kt = 0; kt < D1; kt += 64) {
    // 1. preload all fragments of tile kt from LDS into registers
    bf16x8 af[2][4], bq[2][4];
#pragma unroll
    for (int kk2 = 0; kk2 < 2; ++kk2) {
      // fragment row r has r&7 == llo&7 for every mi/ni -> shared swizzle
      const int sw = (((kk2 * 4) + lhi) ^ (llo & 7)) * 8;
#pragma unroll
      for (int mi = 0; mi < 4; ++mi)
        af[kk2][mi] = *(const bf16x8*)(As + (wm + mi * 16 + llo) * 64 + sw);
#pragma unroll
      for (int ni = 0; ni < 4; ++ni)
        bq[kk2][ni] = *(const bf16x8*)(Bs + (wn + ni * 16 + llo) * 64 + sw);
    }
    // 2. all waves done reading LDS (lgkm drain only; no vm ops outstanding)
    __syncthreads();
    // 3. issue next tile's async loads — they fly during the MFMA phase
    if (kt + 64 < D1) {
#pragma unroll
      for (int i = 0; i < 4; ++i) {
        async_copy16(gA + (size_t)i * 32 * D1 + kt + 64, lA + i * 2048);
        async_copy16(gB + (size_t)i * 32 * D1 + kt + 64, lB + i * 2048);
      }
    }
    // 4. MFMA phase on registers (covers the vmcnt drain at the next barrier)
#pragma unroll
    for (int kk2 = 0; kk2 < 2; ++kk2)
#pragma unroll
      for (int mi = 0; mi < 4; ++mi)
#pragma unroll
        for (int ni = 0; ni < 4; ++ni)
          acc[mi][ni] = __builtin_amdgcn_mfma_f32_16x16x32_bf16(af[kk2][mi], bq[kk2][ni], acc[mi][ni], 0, 0, 0);
    // 5. drain vmcnt (next tile staged) + sync before next preload
    __syncthreads();
  }

  // epilogue: per-row sum of exp(beta * x2). C/D layout: col=lane&15, row=(lane>>4)*4+reg.
#pragma unroll
  for (int mi = 0; mi < 4; ++mi) {
    float rs[4];
#pragma unroll
    for (int r = 0; r < 4; ++r) {
      float v = 0.f;
#pragma unroll
      for (int ni = 0; ni < 4; ++ni)
        v += exp2f(acc[mi][ni][r] * BETA_LOG2E);
      rs[r] = v;
    }
    // sum across the 16 columns held by lanes differing in low 4 bits
#pragma unroll
    for (int m = 1; m < 16; m <<= 1) {
#pragma unroll
      for (int r = 0; r < 4; ++r)
        rs[r] += __shfl_xor(rs[r], m, 64);
    }
    if (llo == 0) {
      int row = row0 + wm + mi * 16 + lhi * 4;
#pragma unroll
      for (int r = 0; r < 4; ++r)
        atomicAdd(&s[row + r], rs[r]);
    }
  }
}

// ---- 5. out[b] = -(1/beta) * log(s[b]) ----
__global__ void finish_kernel(const float* __restrict__ s, float* __restrict__ out) {
  int b = blockIdx.x * 256 + threadIdx.x;
  out[b] = -0.1f * logf(s[b]);
}

extern "C" void kernel_launch(void* const* d_in, const int* in_sizes, int n_in,
                              void* d_out, int out_size, void* d_ws, size_t ws_size,
                              hipStream_t stream) {
  const float* g1 = (const float*)d_in[0];
  const float* W  = (const float*)d_in[1];
  float* out = (float*)d_out;

  char* ws = (char*)d_ws;
  float* s       = (float*)ws;                          // 32768 * 4 = 128 KiB
  float* sq      = (float*)(ws + 131072);               // 4096 * 4  = 16 KiB
  ushort_t* nWt  = (ushort_t*)(ws + 147456);            // 4096*1024*2 = 8 MiB
  ushort_t* g1b  = (ushort_t*)(ws + 147456 + 8388608);  // 32768*1024*2 = 64 MiB

  hipMemsetAsync(ws, 0, 147456, stream);  // zero s + sq

  colnorm_partial<<<dim3(16, 16), 256, 0, stream>>>(W, sq);
  convert_b<<<dim3(64, 16), 256, 0, stream>>>(W, sq, nWt);
  convert_a<<<dim3(16384), 256, 0, stream>>>(g1, g1b);
  gemm_expsum<<<dim3(32, 256), 256, 0, stream>>>(g1b, nWt, s);
  finish_kernel<<<dim3(128), 256, 0, stream>>>(s, out);
}

// Round 5
// 505.492 us; speedup vs baseline: 1.0091x; 1.0091x over previous
//
#include <hip/hip_runtime.h>
#include <hip/hip_bf16.h>
#include <hip/hip_fp8.h>

typedef int i32x8 __attribute__((ext_vector_type(8)));
typedef int i32x4 __attribute__((ext_vector_type(4)));
typedef float f32x4 __attribute__((ext_vector_type(4)));
typedef unsigned char uchar_t;

constexpr int NB = 32768;   // batch rows
constexpr int D1 = 1024;    // K
constexpr int D2 = 4096;    // N
constexpr float BETA_LOG2E = 14.4269504088896340736f; // 10 * log2(e)
constexpr float SCALE_A = 16.0f;        // g1 pre-scale into e4m3 sweet range
constexpr float SCALE_B = 8192.0f;      // dW pre-scale (dW ~ 0.003*N)
constexpr float INV_SCALE = 1.0f / (16.0f * 8192.0f);  // 2^-17

__device__ __forceinline__ uchar_t f32_to_fp8(float f) {
  __hip_fp8_e4m3 q(f);                  // OCP e4m3fn, RNE+satfinite
  return (uchar_t)q.__x;
}

__device__ __forceinline__ void async_copy16(const void* g, void* l) {
  __builtin_amdgcn_global_load_lds(
      (const __attribute__((address_space(1))) void*)g,
      (__attribute__((address_space(3))) void*)l, 16, 0, 0);
}

// ---- 1. column stats of W: sq[j] += sum_k W^2 ; colsum[j] += sum_k W ----
__global__ void colstats(const float* __restrict__ W, float* __restrict__ sq,
                         float* __restrict__ colsum) {
  int j = blockIdx.x * 256 + threadIdx.x;   // gridDim.x = 16
  int k0 = blockIdx.y * 64;                 // gridDim.y = 16
  float a = 0.f, b = 0.f;
#pragma unroll 8
  for (int k = 0; k < 64; ++k) {
    float w = W[(size_t)(k0 + k) * D2 + j];
    a += w * w; b += w;
  }
  atomicAdd(&sq[j], a);
  atomicAdd(&colsum[j], b);
}

// ---- 2. g1 fp32 -> fp8 (x16) + row sums. One block (128 thr) per row. ----
__global__ void convert_a(const float* __restrict__ g1, uchar_t* __restrict__ A8,
                          float* __restrict__ S) {
  int row = blockIdx.x;                // 32768
  int t = threadIdx.x;                 // 128
  const float* src = g1 + (size_t)row * D1 + t * 8;
  float v[8];
  *(float4*)(v)     = *(const float4*)(src);
  *(float4*)(v + 4) = *(const float4*)(src + 4);
  float sum = 0.f;
  union { uchar_t b[8]; uint2 u; } o;
#pragma unroll
  for (int j = 0; j < 8; ++j) { sum += v[j]; o.b[j] = f32_to_fp8(v[j] * SCALE_A); }
  *(uint2*)(A8 + (size_t)row * D1 + t * 8) = o.u;
  // reduce 128 threads -> S[row]
#pragma unroll
  for (int m = 1; m < 64; m <<= 1) sum += __shfl_xor(sum, m, 64);
  __shared__ float part[2];
  if ((t & 63) == 0) part[t >> 6] = sum;
  __syncthreads();
  if (t == 0) S[row] = part[0] + part[1];
}

// ---- 3. mean-subtracted normalize + transpose to fp8:
// mu[j] = colsum[j]*inv/1024; B8t[j][k] = fp8((W[k][j]*inv - mu[j]) * SCALE_B)
__global__ void convert_b(const float* __restrict__ W, const float* __restrict__ sq,
                          const float* __restrict__ colsum,
                          uchar_t* __restrict__ B8t, float* __restrict__ mu) {
  __shared__ float tile[64][65];
  int t = threadIdx.x;                 // 256
  int j0 = blockIdx.x * 64;            // gridDim.x = 64
  int k0 = blockIdx.y * 64;            // gridDim.y = 16
  int c = t & 63, r4 = t >> 6;
#pragma unroll
  for (int s = 0; s < 16; ++s) {
    int k = s * 4 + r4;
    tile[k][c] = W[(size_t)(k0 + k) * D2 + j0 + c];
  }
  __syncthreads();
#pragma unroll
  for (int s = 0; s < 16; ++s) {
    int jj = s * 4 + r4;
    float inv = 1.0f / sqrtf(sq[j0 + jj]);
    float muj = colsum[j0 + jj] * inv * (1.0f / 1024.0f);
    if (k0 == 0 && c == 0) mu[j0 + jj] = muj;
    float dw = tile[c][jj] * inv - muj;
    B8t[(size_t)(j0 + jj) * D1 + k0 + c] = f32_to_fp8(dw * SCALE_B);
  }
}

// ---- 4. fused fp8 GEMM + exp-sum. A8[NB][1024]B, B8t[D2][1024]B (K-major).
// 128x128 tile, BK=128, 256 thr = 4 waves 2x2, each wave 4x4 of
// mfma_scale_f32_16x16x128_f8f6f4 (scale=1.0 via e8m0 127; data pre-scaled,
// undone by INV_SCALE in epilogue). x2 = mu_j*S_b + acc*INV_SCALE.
// Grid: x = col-blocks (32, fast axis) -> A-panel L2 reuse.
// LDS XOR-swizzled (16B seg s at slot s^(row&7)) -> conflict-free b128 reads.
__global__ __launch_bounds__(256, 4)
void gemm_expsum(const uchar_t* __restrict__ A8, const uchar_t* __restrict__ B8t,
                 const float* __restrict__ S, const float* __restrict__ mu,
                 float* __restrict__ s) {
  __shared__ __align__(16) uchar_t As[128 * 128];  // 16 KiB
  __shared__ __align__(16) uchar_t Bs[128 * 128];

  const int t = threadIdx.x;
  const int row0 = blockIdx.y * 128;   // gridDim.y = 256
  const int col0 = blockIdx.x * 128;   // gridDim.x = 32
  const int lane = t & 63;
  const int wave = t >> 6;
  const int wm = (wave >> 1) * 64;
  const int wn = (wave & 1) * 64;
  const int llo = lane & 15, lhi = lane >> 4;

  f32x4 acc[4][4] = {};

  // staging: thread t owns LDS slot (row=t>>3, seg=t&7); fetches global
  // segment (t&7)^(row&7). Sweep i advances row by 32 (row&7 invariant).
  const int srow = t >> 3;
  const int sseg = (t & 7) ^ (srow & 7);
  const uchar_t* gA = A8  + (size_t)(row0 + srow) * D1 + sseg * 16;
  const uchar_t* gB = B8t + (size_t)(col0 + srow) * D1 + sseg * 16;
  uchar_t* lA = As + t * 16;
  uchar_t* lB = Bs + t * 16;

  union Frag { i32x8 v; i32x4 h[2]; };

  for (int kt = 0; kt < D1; kt += 128) {
#pragma unroll
    for (int i = 0; i < 4; ++i) {
      async_copy16(gA + (size_t)i * 32 * D1 + kt, lA + i * 4096);
      async_copy16(gB + (size_t)i * 32 * D1 + kt, lB + i * 4096);
    }
    __syncthreads();   // drains vmcnt(0): staged LDS visible

    // lane's fragment: row m=llo(+16mi), k-window lhi*32..+31 (two 16B segs,
    // stored at seg (lhi*2+h)^(llo&7))
    const int sw0 = ((lhi * 2 + 0) ^ (llo & 7)) * 16;
    const int sw1 = ((lhi * 2 + 1) ^ (llo & 7)) * 16;
    Frag af[4], bq[4];
#pragma unroll
    for (int mi = 0; mi < 4; ++mi) {
      const uchar_t* p = As + (wm + mi * 16 + llo) * 128;
      af[mi].h[0] = *(const i32x4*)(p + sw0);
      af[mi].h[1] = *(const i32x4*)(p + sw1);
    }
#pragma unroll
    for (int ni = 0; ni < 4; ++ni) {
      const uchar_t* p = Bs + (wn + ni * 16 + llo) * 128;
      bq[ni].h[0] = *(const i32x4*)(p + sw0);
      bq[ni].h[1] = *(const i32x4*)(p + sw1);
    }
#pragma unroll
    for (int mi = 0; mi < 4; ++mi)
#pragma unroll
      for (int ni = 0; ni < 4; ++ni)
        acc[mi][ni] = __builtin_amdgcn_mfma_scale_f32_16x16x128_f8f6f4(
            af[mi].v, bq[ni].v, acc[mi][ni],
            0, 0,        // cbsz=fp8(e4m3), blgp=fp8(e4m3)
            0, 127,      // opsel_a, scale_a = e8m0(1.0)
            0, 127);     // opsel_b, scale_b = e8m0(1.0)
    __syncthreads();
  }

  // epilogue: x2 = mu_j*S_b + acc*2^-17; per-row sum of exp2(x2*beta*log2e).
  // C/D layout (16x16): col = lane&15, row = (lane>>4)*4 + reg.
  float muv[4];
#pragma unroll
  for (int ni = 0; ni < 4; ++ni) muv[ni] = mu[col0 + wn + ni * 16 + llo];

#pragma unroll
  for (int mi = 0; mi < 4; ++mi) {
    const int row = row0 + wm + mi * 16 + lhi * 4;
    float4 sv = *(const float4*)(S + row);
    float sarr[4] = {sv.x, sv.y, sv.z, sv.w};
    float rs[4];
#pragma unroll
    for (int r = 0; r < 4; ++r) {
      float v = 0.f;
#pragma unroll
      for (int ni = 0; ni < 4; ++ni) {
        float x2 = fmaf(acc[mi][ni][r], INV_SCALE, muv[ni] * sarr[r]);
        v += exp2f(x2 * BETA_LOG2E);
      }
      rs[r] = v;
    }
#pragma unroll
    for (int m = 1; m < 16; m <<= 1) {
#pragma unroll
      for (int r = 0; r < 4; ++r)
        rs[r] += __shfl_xor(rs[r], m, 64);
    }
    if (llo == 0) {
#pragma unroll
      for (int r = 0; r < 4; ++r)
        atomicAdd(&s[row + r], rs[r]);
    }
  }
}

// ---- 5. out[b] = -(1/beta) * log(s[b]) ----
__global__ void finish_kernel(const float* __restrict__ s, float* __restrict__ out) {
  int b = blockIdx.x * 256 + threadIdx.x;
  out[b] = -0.1f * logf(s[b]);
}

extern "C" void kernel_launch(void* const* d_in, const int* in_sizes, int n_in,
                              void* d_out, int out_size, void* d_ws, size_t ws_size,
                              hipStream_t stream) {
  const float* g1 = (const float*)d_in[0];
  const float* W  = (const float*)d_in[1];
  float* out = (float*)d_out;

  char* ws = (char*)d_ws;
  float* s       = (float*)ws;                    // 32768*4 = 131072
  float* sq      = (float*)(ws + 131072);         // 4096*4
  float* colsum  = (float*)(ws + 147456);         // 4096*4
  float* mu      = (float*)(ws + 163840);         // 4096*4
  float* S       = (float*)(ws + 180224);         // 32768*4
  uchar_t* A8    = (uchar_t*)(ws + 311296);       // 32 MiB
  uchar_t* B8t   = (uchar_t*)(ws + 311296 + 33554432);  // 4 MiB

  hipMemsetAsync(ws, 0, 180224, stream);  // zero s, sq, colsum (mu overwritten)

  colstats<<<dim3(16, 16), 256, 0, stream>>>(W, sq, colsum);
  convert_b<<<dim3(64, 16), 256, 0, stream>>>(W, sq, colsum, B8t, mu);
  convert_a<<<dim3(32768), 128, 0, stream>>>(g1, A8, S);
  gemm_expsum<<<dim3(32, 256), 256, 0, stream>>>(A8, B8t, S, mu, s);
  finish_kernel<<<dim3(128), 256, 0, stream>>>(s, out);
}

// Round 7
// 421.581 us; speedup vs baseline: 1.2100x; 1.1990x over previous
//
#include <hip/hip_runtime.h>
#include <hip/hip_bf16.h>
#include <hip/hip_fp8.h>

typedef int i32x8 __attribute__((ext_vector_type(8)));
typedef int i32x4 __attribute__((ext_vector_type(4)));
typedef float f32x4 __attribute__((ext_vector_type(4)));
typedef unsigned char uchar_t;

constexpr int NB = 32768;   // batch rows
constexpr int D1 = 1024;    // K
constexpr int D2 = 4096;    // N
constexpr float BETA_LOG2E = 14.4269504088896340736f; // 10 * log2(e)
constexpr float SCALE_A = 16.0f;        // g1 pre-scale into e4m3 sweet range
constexpr float SCALE_B = 8192.0f;      // dW pre-scale (dW ~ 0.003*N)
constexpr float INV_SCALE = 1.0f / (16.0f * 8192.0f);  // 2^-17

__device__ __forceinline__ uchar_t f32_to_fp8(float f) {
  __hip_fp8_e4m3 q(f);                  // OCP e4m3fn, RNE+satfinite
  return (uchar_t)q.__x;
}

__device__ __forceinline__ void async_copy16(const void* g, void* l) {
  __builtin_amdgcn_global_load_lds(
      (const __attribute__((address_space(1))) void*)g,
      (__attribute__((address_space(3))) void*)l, 16, 0, 0);
}

// ---- 1. column stats of W: sq[j] += sum_k W^2 ; colsum[j] += sum_k W ----
__global__ void colstats(const float* __restrict__ W, float* __restrict__ sq,
                         float* __restrict__ colsum) {
  int j = blockIdx.x * 256 + threadIdx.x;   // gridDim.x = 16
  int k0 = blockIdx.y * 64;                 // gridDim.y = 16
  float a = 0.f, b = 0.f;
#pragma unroll 8
  for (int k = 0; k < 64; ++k) {
    float w = W[(size_t)(k0 + k) * D2 + j];
    a += w * w; b += w;
  }
  atomicAdd(&sq[j], a);
  atomicAdd(&colsum[j], b);
}

// ---- 2. g1 fp32 -> fp8 (x16) + row sums. One block (128 thr) per row. ----
__global__ void convert_a(const float* __restrict__ g1, uchar_t* __restrict__ A8,
                          float* __restrict__ S) {
  int row = blockIdx.x;                // 32768
  int t = threadIdx.x;                 // 128
  const float* src = g1 + (size_t)row * D1 + t * 8;
  float v[8];
  *(float4*)(v)     = *(const float4*)(src);
  *(float4*)(v + 4) = *(const float4*)(src + 4);
  float sum = 0.f;
  union { uchar_t b[8]; uint2 u; } o;
#pragma unroll
  for (int j = 0; j < 8; ++j) { sum += v[j]; o.b[j] = f32_to_fp8(v[j] * SCALE_A); }
  *(uint2*)(A8 + (size_t)row * D1 + t * 8) = o.u;
  // reduce 128 threads -> S[row]
#pragma unroll
  for (int m = 1; m < 64; m <<= 1) sum += __shfl_xor(sum, m, 64);
  __shared__ float part[2];
  if ((t & 63) == 0) part[t >> 6] = sum;
  __syncthreads();
  if (t == 0) S[row] = part[0] + part[1];
}

// ---- 3. mean-subtracted normalize + transpose to fp8:
// mu[j] = colsum[j]*inv/1024; B8t[j][k] = fp8((W[k][j]*inv - mu[j]) * SCALE_B)
__global__ void convert_b(const float* __restrict__ W, const float* __restrict__ sq,
                          const float* __restrict__ colsum,
                          uchar_t* __restrict__ B8t, float* __restrict__ mu) {
  __shared__ float tile[64][65];
  int t = threadIdx.x;                 // 256
  int j0 = blockIdx.x * 64;            // gridDim.x = 64
  int k0 = blockIdx.y * 64;            // gridDim.y = 16
  int c = t & 63, r4 = t >> 6;
#pragma unroll
  for (int s = 0; s < 16; ++s) {
    int k = s * 4 + r4;
    tile[k][c] = W[(size_t)(k0 + k) * D2 + j0 + c];
  }
  __syncthreads();
#pragma unroll
  for (int s = 0; s < 16; ++s) {
    int jj = s * 4 + r4;
    float inv = 1.0f / sqrtf(sq[j0 + jj]);
    float muj = colsum[j0 + jj] * inv * (1.0f / 1024.0f);
    if (k0 == 0 && c == 0) mu[j0 + jj] = muj;
    float dw = tile[c][jj] * inv - muj;
    B8t[(size_t)(j0 + jj) * D1 + k0 + c] = f32_to_fp8(dw * SCALE_B);
  }
}

// ---- 4. fused fp8 GEMM + exp-sum. A8[NB][1024]B, B8t[D2][1024]B (K-major).
// 128x128 tile, BK=128, 256 thr = 4 waves 2x2, each wave 4x4 of
// mfma_scale_f32_16x16x128_f8f6f4 (scale=1.0 via e8m0 127; data pre-scaled,
// undone by INV_SCALE in epilogue). x2 = mu_j*S_b + acc*INV_SCALE.
// DOUBLE-BUFFERED LDS, one barrier per K-iter, prefetch issued right after the
// barrier into the buffer nobody is reading — in-flight global_load_lds writes
// and LDS fragment reads touch DISJOINT buffers, so no compiler scheduling of
// the void async-copy intrinsic across barriers can corrupt data (R6's
// single-buffer version raced under graph replay).
// LDS XOR-swizzled (16B seg s at slot s^(row&7)) -> conflict-free b128 reads.
__global__ __launch_bounds__(256, 2)
void gemm_expsum(const uchar_t* __restrict__ A8, const uchar_t* __restrict__ B8t,
                 const float* __restrict__ S, const float* __restrict__ mu,
                 float* __restrict__ s) {
  __shared__ __align__(16) uchar_t As[2 * 128 * 128];  // 32 KiB
  __shared__ __align__(16) uchar_t Bs[2 * 128 * 128];  // 32 KiB

  const int t = threadIdx.x;
  const int row0 = blockIdx.y * 128;   // gridDim.y = 256
  const int col0 = blockIdx.x * 128;   // gridDim.x = 32 (fast axis: A-panel L2 reuse)
  const int lane = t & 63;
  const int wave = t >> 6;
  const int wm = (wave >> 1) * 64;
  const int wn = (wave & 1) * 64;
  const int llo = lane & 15, lhi = lane >> 4;

  f32x4 acc[4][4] = {};

  // staging: thread t owns LDS slot (row=t>>3, seg=t&7); fetches global
  // segment (t&7)^(row&7). Sweep i advances row by 32 (row&7 invariant).
  const int srow = t >> 3;
  const int sseg = (t & 7) ^ (srow & 7);
  const uchar_t* gA = A8  + (size_t)(row0 + srow) * D1 + sseg * 16;
  const uchar_t* gB = B8t + (size_t)(col0 + srow) * D1 + sseg * 16;

  // lane's fragment: row m=llo(+16mi), k-window lhi*32..+31 = two 16B segs,
  // stored swizzled at seg (lhi*2+h)^(llo&7)
  const int sw0 = ((lhi * 2 + 0) ^ (llo & 7)) * 16;
  const int sw1 = ((lhi * 2 + 1) ^ (llo & 7)) * 16;

  // prologue: stage tile 0 into buffer 0
#pragma unroll
  for (int i = 0; i < 4; ++i) {
    async_copy16(gA + (size_t)i * 32 * D1, As + t * 16 + i * 4096);
    async_copy16(gB + (size_t)i * 32 * D1, Bs + t * 16 + i * 4096);
  }

  int p = 0;
  for (int kt = 0; kt < D1; kt += 128, p ^= 1) {
    // drains vmcnt(0): copies into buf p landed; all waves done reading buf p^1
    __syncthreads();
    // prefetch next tile into buf p^1 (nobody reads it until after next barrier)
    if (kt + 128 < D1) {
#pragma unroll
      for (int i = 0; i < 4; ++i) {
        async_copy16(gA + (size_t)i * 32 * D1 + kt + 128,
                     As + (p ^ 1) * 16384 + t * 16 + i * 4096);
        async_copy16(gB + (size_t)i * 32 * D1 + kt + 128,
                     Bs + (p ^ 1) * 16384 + t * 16 + i * 4096);
      }
    }
    // fragments from buf p
    const uchar_t* baseA = As + p * 16384;
    const uchar_t* baseB = Bs + p * 16384;
    i32x8 af[4], bq[4];
#pragma unroll
    for (int mi = 0; mi < 4; ++mi) {
      const uchar_t* q = baseA + (wm + mi * 16 + llo) * 128;
      i32x4 h0 = *(const i32x4*)(q + sw0);
      i32x4 h1 = *(const i32x4*)(q + sw1);
      af[mi] = __builtin_shufflevector(h0, h1, 0, 1, 2, 3, 4, 5, 6, 7);
    }
#pragma unroll
    for (int ni = 0; ni < 4; ++ni) {
      const uchar_t* q = baseB + (wn + ni * 16 + llo) * 128;
      i32x4 h0 = *(const i32x4*)(q + sw0);
      i32x4 h1 = *(const i32x4*)(q + sw1);
      bq[ni] = __builtin_shufflevector(h0, h1, 0, 1, 2, 3, 4, 5, 6, 7);
    }
#pragma unroll
    for (int mi = 0; mi < 4; ++mi)
#pragma unroll
      for (int ni = 0; ni < 4; ++ni)
        acc[mi][ni] = __builtin_amdgcn_mfma_scale_f32_16x16x128_f8f6f4(
            af[mi], bq[ni], acc[mi][ni],
            0, 0,        // cbsz=fp8(e4m3), blgp=fp8(e4m3)
            0, 127,      // opsel_a, scale_a = e8m0(1.0)
            0, 127);     // opsel_b, scale_b = e8m0(1.0)
  }

  // epilogue: x2 = mu_j*S_b + acc*2^-17; per-row sum of exp2(x2*beta*log2e).
  // C/D layout (16x16): col = lane&15, row = (lane>>4)*4 + reg.
  float muv[4];
#pragma unroll
  for (int ni = 0; ni < 4; ++ni) muv[ni] = mu[col0 + wn + ni * 16 + llo];

#pragma unroll
  for (int mi = 0; mi < 4; ++mi) {
    const int row = row0 + wm + mi * 16 + lhi * 4;
    float4 sv = *(const float4*)(S + row);
    float sarr[4] = {sv.x, sv.y, sv.z, sv.w};
    float rs[4];
#pragma unroll
    for (int r = 0; r < 4; ++r) {
      float v = 0.f;
#pragma unroll
      for (int ni = 0; ni < 4; ++ni) {
        float x2 = fmaf(acc[mi][ni][r], INV_SCALE, muv[ni] * sarr[r]);
        v += exp2f(x2 * BETA_LOG2E);
      }
      rs[r] = v;
    }
#pragma unroll
    for (int m = 1; m < 16; m <<= 1) {
#pragma unroll
      for (int r = 0; r < 4; ++r)
        rs[r] += __shfl_xor(rs[r], m, 64);
    }
    if (llo == 0) {
#pragma unroll
      for (int r = 0; r < 4; ++r)
        atomicAdd(&s[row + r], rs[r]);
    }
  }
}

// ---- 5. out[b] = -(1/beta) * log(s[b]) ----
__global__ void finish_kernel(const float* __restrict__ s, float* __restrict__ out) {
  int b = blockIdx.x * 256 + threadIdx.x;
  out[b] = -0.1f * logf(s[b]);
}

extern "C" void kernel_launch(void* const* d_in, const int* in_sizes, int n_in,
                              void* d_out, int out_size, void* d_ws, size_t ws_size,
                              hipStream_t stream) {
  const float* g1 = (const float*)d_in[0];
  const float* W  = (const float*)d_in[1];
  float* out = (float*)d_out;

  char* ws = (char*)d_ws;
  float* s       = (float*)ws;                    // 32768*4 = 131072
  float* sq      = (float*)(ws + 131072);         // 4096*4
  float* colsum  = (float*)(ws + 147456);         // 4096*4
  float* mu      = (float*)(ws + 163840);         // 4096*4
  float* S       = (float*)(ws + 180224);         // 32768*4
  uchar_t* A8    = (uchar_t*)(ws + 311296);       // 32 MiB
  uchar_t* B8t   = (uchar_t*)(ws + 311296 + 33554432);  // 4 MiB

  hipMemsetAsync(ws, 0, 180224, stream);  // zero s, sq, colsum (mu overwritten)

  colstats<<<dim3(16, 16), 256, 0, stream>>>(W, sq, colsum);
  convert_b<<<dim3(64, 16), 256, 0, stream>>>(W, sq, colsum, B8t, mu);
  convert_a<<<dim3(32768), 128, 0, stream>>>(g1, A8, S);
  gemm_expsum<<<dim3(32, 256), 256, 0, stream>>>(A8, B8t, S, mu, s);
  finish_kernel<<<dim3(128), 256, 0, stream>>>(s, out);
}